// Round 3
// baseline (1026.391 us; speedup 1.0000x reference)
//
#include <hip/hip_runtime.h>

// BlockSelfAttention: B=8, H=W=256, C=128, P=8 -> 8192 windows, L=64, 4 heads x d=32.
// Fully fused: LN -> QKV (MFMA) -> per-head attention -> out-proj -> gamma.
// One block per window, 256 threads = 4 waves, wave w owns head w.
// R3: FULL two-term bf16 splits (hi/lo) on every tensor (Xn, Wqkv, Q, K, V, P, O, Wout),
// each hi/lo pair in its own write-once LDS buffer -> effectively fp32 end-to-end.
// 156 KB LDS -> 1 block/CU this round (correctness first; trim next rounds).

typedef short    short8  __attribute__((ext_vector_type(8)));
typedef __bf16   bf16x8  __attribute__((ext_vector_type(8)));
typedef float    floatx4 __attribute__((ext_vector_type(4)));

#define LOG2E 1.44269504088896f
#define ATTN_SCALE 0.17677669529663687f   // 1/sqrt(32)

// LDS byte offsets. [64][136] bf16 regions = 17408 B; VT [32][72]x4 heads = 18432 B;
// P [16][72]x4 waves = 9216 B. Total 159744 <= 163840 (160 KiB).
#define A_OFF   0        // Xn_hi (ph1-2) -> Q_hi (post-b1)
#define B_OFF   17408    // Xn_lo (ph1-2) -> Q_lo (post-b1)
#define KH_OFF  34816
#define KL_OFF  52224
#define VTH_OFF 69632    // per head stride 4608 B
#define VTL_OFF 88064
#define PH_OFF  106496   // per wave stride 2304 B
#define PL_OFF  115712
#define OH_OFF  124928
#define OL_OFF  142336
#define SMEM_BYTES 159744

__device__ __forceinline__ unsigned short f2bf(float f) {
  unsigned u = __builtin_bit_cast(unsigned, f);
  u += 0x7fffu + ((u >> 16) & 1u);            // round-to-nearest-even
  return (unsigned short)(u >> 16);
}
__device__ __forceinline__ float bf2f(unsigned short h) {
  return __builtin_bit_cast(float, ((unsigned)h) << 16);
}

__device__ __forceinline__ floatx4 mfma_bf16(short8 a, short8 b, floatx4 c) {
  return __builtin_amdgcn_mfma_f32_16x16x32_bf16(
      __builtin_bit_cast(bf16x8, a), __builtin_bit_cast(bf16x8, b), c, 0, 0, 0);
}

// ws layout (unsigned short): [0,49152) wqkv_hi | [49152,65536) wout_hi
//                             [65536,114688) wqkv_lo | [114688,131072) wout_lo
__global__ void convert_weights(const float* __restrict__ ipw,
                                const float* __restrict__ opw,
                                unsigned short* __restrict__ ws) {
  int i = blockIdx.x * 256 + threadIdx.x;     // 0..65535
  float v = (i < 49152) ? ipw[i] : opw[i - 49152];
  unsigned short hi = f2bf(v);
  ws[i] = hi;
  ws[65536 + i] = f2bf(v - bf2f(hi));
}

__global__ __launch_bounds__(256, 1)
void attn_kernel(const float* __restrict__ x,
                 const float* __restrict__ ln_w,
                 const float* __restrict__ ln_b,
                 const float* __restrict__ in_proj_b,
                 const float* __restrict__ out_proj_b,
                 const float* __restrict__ gamma,
                 const unsigned short* __restrict__ wqkv_h,   // [384][128]
                 const unsigned short* __restrict__ wqkv_l,
                 const unsigned short* __restrict__ wout_h,   // [128][128]
                 const unsigned short* __restrict__ wout_l,
                 float* __restrict__ out) {
  __shared__ uint4 smem4[SMEM_BYTES / 16];
  char* smem = (char*)smem4;

  const int t    = threadIdx.x;
  const int lane = t & 63;
  const int ln   = lane & 15;     // MFMA n/m lane index
  const int hg   = lane >> 4;     // MFMA k-group / row-group
  const int w    = t >> 6;        // wave id == head id

  const int win = blockIdx.x;
  const int bb = win >> 10, wh = (win >> 5) & 31, ww = win & 31;
  const size_t gbase = ((size_t)(bb * 256 + wh * 8) * 256 + (size_t)(ww * 8)) * 128;

  // ---------------- Phase 1: LayerNorm (fp32) -> Xn hi/lo bf16 in LDS ----------------
  {
    const int p = t >> 2, sub = t & 3;        // 4 threads per pixel, 32 ch each
    const int py = p >> 3, px = p & 7;
    const float* xp = x + gbase + (size_t)(py * 256 + px) * 128 + sub * 32;
    float4 v[8];
#pragma unroll
    for (int j = 0; j < 8; j++) v[j] = *(const float4*)(xp + j * 4);
    float s = 0.f, s2 = 0.f;
#pragma unroll
    for (int j = 0; j < 8; j++) {
      float4 a = v[j];
      s  += a.x + a.y + a.z + a.w;
      s2 += a.x * a.x + a.y * a.y + a.z * a.z + a.w * a.w;
    }
    s  += __shfl_xor(s, 1);  s  += __shfl_xor(s, 2);
    s2 += __shfl_xor(s2, 1); s2 += __shfl_xor(s2, 2);
    const float mu = s * (1.f / 128.f);
    const float var = s2 * (1.f / 128.f) - mu * mu;
    const float rs = rsqrtf(var + 1e-5f);
#pragma unroll
    for (int j = 0; j < 8; j++) {
      int c = sub * 32 + j * 4;
      float4 lw = *(const float4*)(ln_w + c);
      float4 lb = *(const float4*)(ln_b + c);
      float4 a = v[j];
      float o0 = (a.x - mu) * rs * lw.x + lb.x;
      float o1 = (a.y - mu) * rs * lw.y + lb.y;
      float o2 = (a.z - mu) * rs * lw.z + lb.z;
      float o3 = (a.w - mu) * rs * lw.w + lb.w;
      unsigned short h0 = f2bf(o0), h1 = f2bf(o1), h2 = f2bf(o2), h3 = f2bf(o3);
      unsigned hi01 = (unsigned)h0 | ((unsigned)h1 << 16);
      unsigned hi23 = (unsigned)h2 | ((unsigned)h3 << 16);
      unsigned lo01 = (unsigned)f2bf(o0 - bf2f(h0)) | ((unsigned)f2bf(o1 - bf2f(h1)) << 16);
      unsigned lo23 = (unsigned)f2bf(o2 - bf2f(h2)) | ((unsigned)f2bf(o3 - bf2f(h3)) << 16);
      *(uint2*)(smem + A_OFF + (p * 136 + c) * 2) = make_uint2(hi01, hi23);
      *(uint2*)(smem + B_OFF + (p * 136 + c) * 2) = make_uint2(lo01, lo23);
    }
  }
  __syncthreads();   // b0: Xn hi/lo ready

  // ---------------- Phase 2: QKV = (Xh+Xl) @ (Wh+Wl)^T  (3 MFMAs/term) ----------------
  const int dcol[6] = { w * 32, w * 32 + 16,
                        128 + w * 32, 128 + w * 32 + 16,
                        256 + w * 32, 256 + w * 32 + 16 };
  floatx4 acc[6][4];
#pragma unroll
  for (int nt = 0; nt < 6; nt++)
#pragma unroll
    for (int mi = 0; mi < 4; mi++) acc[nt][mi] = (floatx4){0.f, 0.f, 0.f, 0.f};

#pragma unroll
  for (int kk = 0; kk < 4; kk++) {
    short8 ah[4], al[4];
#pragma unroll
    for (int mi = 0; mi < 4; mi++) {
      const int idx = ((mi * 16 + ln) * 136 + kk * 32 + hg * 8) * 2;
      ah[mi] = *(const short8*)(smem + A_OFF + idx);
      al[mi] = *(const short8*)(smem + B_OFF + idx);
    }
#pragma unroll
    for (int nt = 0; nt < 6; nt++) {
      const int widx = (dcol[nt] + ln) * 128 + kk * 32 + hg * 8;
      short8 bh = *(const short8*)(wqkv_h + widx);
      short8 bl = *(const short8*)(wqkv_l + widx);
#pragma unroll
      for (int mi = 0; mi < 4; mi++) {
        acc[nt][mi] = mfma_bf16(ah[mi], bl, acc[nt][mi]);
        acc[nt][mi] = mfma_bf16(al[mi], bh, acc[nt][mi]);
        acc[nt][mi] = mfma_bf16(ah[mi], bh, acc[nt][mi]);
      }
    }
  }
  __syncthreads();   // b1: all Xn reads done; A/B reused for Q hi/lo

  // epilogue: +bias (fp32); split hi/lo; Q->A/B, K->KH/KL, V^T->VTH/VTL (all write-once)
#pragma unroll
  for (int nt = 0; nt < 6; nt++) {
    const int d = dcol[nt] + ln;
    const float bias = in_proj_b[d];
#pragma unroll
    for (int mi = 0; mi < 4; mi++)
#pragma unroll
      for (int r = 0; r < 4; r++) {
        const int l = mi * 16 + hg * 4 + r;
        const float val = acc[nt][mi][r] + bias;
        const unsigned short hv = f2bf(val);
        const unsigned short lv = f2bf(val - bf2f(hv));
        if (nt < 2) {
          const int idx = (l * 136 + d) * 2;
          *(unsigned short*)(smem + A_OFF + idx) = hv;
          *(unsigned short*)(smem + B_OFF + idx) = lv;
        } else if (nt < 4) {
          const int idx = (l * 136 + (d - 128)) * 2;
          *(unsigned short*)(smem + KH_OFF + idx) = hv;
          *(unsigned short*)(smem + KL_OFF + idx) = lv;
        } else {
          const int idx = w * 4608 + ((d - 256 - w * 32) * 72 + l) * 2;
          *(unsigned short*)(smem + VTH_OFF + idx) = hv;
          *(unsigned short*)(smem + VTL_OFF + idx) = lv;
        }
      }
  }

  // ---------------- Phase 3: attention (wave-private head; reads own writes only) ------
  short8 kbh[4], kbl[4], qah[4], qal[4], vbh[2][2], vbl[2][2];
#pragma unroll
  for (int n2 = 0; n2 < 4; n2++) {
    const int idx = ((n2 * 16 + ln) * 136 + w * 32 + hg * 8) * 2;
    kbh[n2] = *(const short8*)(smem + KH_OFF + idx);
    kbl[n2] = *(const short8*)(smem + KL_OFF + idx);
  }
#pragma unroll
  for (int mi = 0; mi < 4; mi++) {
    const int idx = ((mi * 16 + ln) * 136 + w * 32 + hg * 8) * 2;
    qah[mi] = *(const short8*)(smem + A_OFF + idx);
    qal[mi] = *(const short8*)(smem + B_OFF + idx);
  }
#pragma unroll
  for (int ni = 0; ni < 2; ni++)
#pragma unroll
    for (int k2 = 0; k2 < 2; k2++) {
      const int idx = w * 4608 + ((ni * 16 + ln) * 72 + k2 * 32 + hg * 8) * 2;
      vbh[ni][k2] = *(const short8*)(smem + VTH_OFF + idx);
      vbl[ni][k2] = *(const short8*)(smem + VTL_OFF + idx);
    }

  floatx4 oacc[4][2];
#pragma unroll
  for (int mi = 0; mi < 4; mi++)
#pragma unroll
    for (int ni = 0; ni < 2; ni++) oacc[mi][ni] = (floatx4){0.f, 0.f, 0.f, 0.f};

  char* phbuf = smem + PH_OFF + w * 2304;
  char* plbuf = smem + PL_OFF + w * 2304;
#pragma unroll
  for (int mi = 0; mi < 4; mi++) {
    floatx4 s[4];
    const floatx4 z4 = (floatx4){0.f, 0.f, 0.f, 0.f};
#pragma unroll
    for (int n2 = 0; n2 < 4; n2++) {
      s[n2] = mfma_bf16(qal[mi], kbh[n2], z4);
      s[n2] = mfma_bf16(qah[mi], kbl[n2], s[n2]);
      s[n2] = mfma_bf16(qah[mi], kbh[n2], s[n2]);
    }
    // softmax per row (rows on fixed 16-lane group; cols = 4 tiles x 16 lanes)
#pragma unroll
    for (int r = 0; r < 4; r++) {
      float v0 = s[0][r] * ATTN_SCALE, v1 = s[1][r] * ATTN_SCALE;
      float v2 = s[2][r] * ATTN_SCALE, v3 = s[3][r] * ATTN_SCALE;
      float m = fmaxf(fmaxf(v0, v1), fmaxf(v2, v3));
      m = fmaxf(m, __shfl_xor(m, 1)); m = fmaxf(m, __shfl_xor(m, 2));
      m = fmaxf(m, __shfl_xor(m, 4)); m = fmaxf(m, __shfl_xor(m, 8));
      v0 = exp2f((v0 - m) * LOG2E); v1 = exp2f((v1 - m) * LOG2E);
      v2 = exp2f((v2 - m) * LOG2E); v3 = exp2f((v3 - m) * LOG2E);
      float sum = v0 + v1 + v2 + v3;
      sum += __shfl_xor(sum, 1); sum += __shfl_xor(sum, 2);
      sum += __shfl_xor(sum, 4); sum += __shfl_xor(sum, 8);
      const float inv = 1.0f / sum;
      s[0][r] = v0 * inv; s[1][r] = v1 * inv; s[2][r] = v2 * inv; s[3][r] = v3 * inv;
    }
    // P hi/lo -> separate LDS buffers (write-once), then A-frag reads
#pragma unroll
    for (int n2 = 0; n2 < 4; n2++)
#pragma unroll
      for (int r = 0; r < 4; r++) {
        const float p = s[n2][r];
        const unsigned short hv = f2bf(p);
        const int idx = ((hg * 4 + r) * 72 + n2 * 16 + ln) * 2;
        *(unsigned short*)(phbuf + idx) = hv;
        *(unsigned short*)(plbuf + idx) = f2bf(p - bf2f(hv));
      }
    short8 pah[2], pal[2];
#pragma unroll
    for (int k2 = 0; k2 < 2; k2++) {
      const int idx = (ln * 72 + k2 * 32 + hg * 8) * 2;
      pah[k2] = *(const short8*)(phbuf + idx);
      pal[k2] = *(const short8*)(plbuf + idx);
    }
#pragma unroll
    for (int ni = 0; ni < 2; ni++)
#pragma unroll
      for (int k2 = 0; k2 < 2; k2++) {
        oacc[mi][ni] = mfma_bf16(pal[k2], vbh[ni][k2], oacc[mi][ni]);
        oacc[mi][ni] = mfma_bf16(pah[k2], vbl[ni][k2], oacc[mi][ni]);
        oacc[mi][ni] = mfma_bf16(pah[k2], vbh[ni][k2], oacc[mi][ni]);
      }
  }

  // write O hi/lo to dedicated regions (wave-private columns)
#pragma unroll
  for (int mi = 0; mi < 4; mi++)
#pragma unroll
    for (int ni = 0; ni < 2; ni++)
#pragma unroll
      for (int r = 0; r < 4; r++) {
        const float v = oacc[mi][ni][r];
        const unsigned short hv = f2bf(v);
        const int idx = ((mi * 16 + hg * 4 + r) * 136 + w * 32 + ni * 16 + ln) * 2;
        *(unsigned short*)(smem + OH_OFF + idx) = hv;
        *(unsigned short*)(smem + OL_OFF + idx) = f2bf(v - bf2f(hv));
      }
  __syncthreads();   // b2: O complete

  // ---------------- Phase 4: Y = (Oh+Ol) @ (Wh+Wl)^T, +bias, *gamma, store -------------
  floatx4 y[4][2];
#pragma unroll
  for (int mi = 0; mi < 4; mi++)
#pragma unroll
    for (int nt = 0; nt < 2; nt++) y[mi][nt] = (floatx4){0.f, 0.f, 0.f, 0.f};
#pragma unroll
  for (int kk = 0; kk < 4; kk++) {
    short8 oh[4], ol[4];
#pragma unroll
    for (int mi = 0; mi < 4; mi++) {
      const int idx = ((mi * 16 + ln) * 136 + kk * 32 + hg * 8) * 2;
      oh[mi] = *(const short8*)(smem + OH_OFF + idx);
      ol[mi] = *(const short8*)(smem + OL_OFF + idx);
    }
#pragma unroll
    for (int nt = 0; nt < 2; nt++) {
      const int widx = (w * 32 + nt * 16 + ln) * 128 + kk * 32 + hg * 8;
      short8 wbh = *(const short8*)(wout_h + widx);
      short8 wbl = *(const short8*)(wout_l + widx);
#pragma unroll
      for (int mi = 0; mi < 4; mi++) {
        y[mi][nt] = mfma_bf16(ol[mi], wbh, y[mi][nt]);
        y[mi][nt] = mfma_bf16(oh[mi], wbl, y[mi][nt]);
        y[mi][nt] = mfma_bf16(oh[mi], wbh, y[mi][nt]);
      }
    }
  }
#pragma unroll
  for (int nt = 0; nt < 2; nt++) {
    const int d = w * 32 + nt * 16 + ln;
    const float bo = out_proj_b[d];
    const float g = gamma[d];
#pragma unroll
    for (int mi = 0; mi < 4; mi++)
#pragma unroll
      for (int r = 0; r < 4; r++) {
        const int l = mi * 16 + hg * 4 + r;
        const int py = l >> 3, px = l & 7;
        out[gbase + (size_t)(py * 256 + px) * 128 + d] = (y[mi][nt][r] + bo) * g;
      }
  }
}

extern "C" void kernel_launch(void* const* d_in, const int* in_sizes, int n_in,
                              void* d_out, int out_size, void* d_ws, size_t ws_size,
                              hipStream_t stream) {
  const float* x     = (const float*)d_in[0];
  const float* ln_w  = (const float*)d_in[1];
  const float* ln_b  = (const float*)d_in[2];
  const float* ipw   = (const float*)d_in[3];
  const float* ipb   = (const float*)d_in[4];
  const float* opw   = (const float*)d_in[5];
  const float* opb   = (const float*)d_in[6];
  const float* gamma = (const float*)d_in[7];
  unsigned short* wbf = (unsigned short*)d_ws;

  convert_weights<<<256, 256, 0, stream>>>(ipw, opw, wbf);
  attn_kernel<<<8192, 256, 0, stream>>>(x, ln_w, ln_b, ipb, opb, gamma,
                                        wbf, wbf + 65536,          // wqkv hi/lo
                                        wbf + 49152, wbf + 114688, // wout hi/lo
                                        (float*)d_out);
}